// Round 3
// baseline (134.900 us; speedup 1.0000x reference)
//
#include <hip/hip_runtime.h>

#define B_  8
#define C_  256
#define N_  16384
#define NM_ 128
#define LDK 40   // padded row stride (halves)

typedef _Float16 f16x8 __attribute__((ext_vector_type(8)));
typedef float    f32x4 __attribute__((ext_vector_type(4)));

// ---------------- kernel 1: split-K fp16x2 MFMA GEMM + fused norm partials ----------------
// 512 threads (8 waves), 128x128 tile, KB=32. Each wave owns a 32x64 sub-tile.
__global__ __launch_bounds__(512, 4) void gemm_f16_kernel(const float* __restrict__ X,
                                                          const float* __restrict__ Y,
                                                          float* __restrict__ Gp,
                                                          float* __restrict__ x2p,
                                                          float* __restrict__ y2p,
                                                          int Kchunk) {
    __shared__ _Float16 aH[128][LDK];
    __shared__ _Float16 aL[128][LDK];
    __shared__ _Float16 bH[128][LDK];
    __shared__ _Float16 bL[128][LDK];

    int lin = blockIdx.x;
    int jt = lin & 1, it = (lin >> 1) & 1, b = (lin >> 2) & 7, ks = lin >> 5;
    int k0 = ks * Kchunk;

    int t = threadIdx.x;
    int lane = t & 63;
    int wid = t >> 6;                 // 8 waves
    int wm = wid >> 1, wn = wid & 1;  // wave tile: rows wm*32.., cols wn*64..

    int srow = t >> 2;                // staging row 0..127
    int skq = (t & 3) * 8;            // staging k sub-chunk: 0,8,16,24

    const float* xp = X + ((size_t)(b * C_) + it * 128 + srow) * N_ + k0 + skq;
    const float* yp = Y + ((size_t)(b * C_) + jt * 128 + srow) * N_ + k0 + skq;

    f32x4 acc[2][4] = {};
    float sx = 0.f, sy = 0.f;

    float4 VA[2], VB[2];
    VA[0] = *(const float4*)(xp);
    VA[1] = *(const float4*)(xp + 4);
    VB[0] = *(const float4*)(yp);
    VB[1] = *(const float4*)(yp + 4);

    for (int kk = 0; kk < Kchunk; kk += 32) {
        // convert staged registers to hi/lo fp16, accumulate norms
        _Float16 ha[8], la[8], hb[8], lb[8];
        const float* fa = (const float*)VA;
        const float* fb = (const float*)VB;
#pragma unroll
        for (int e = 0; e < 8; ++e) {
            float v = fa[e];
            _Float16 h = (_Float16)v;
            ha[e] = h; la[e] = (_Float16)(v - (float)h);
            sx += v * v;
            float w = fb[e];
            _Float16 h2 = (_Float16)w;
            hb[e] = h2; lb[e] = (_Float16)(w - (float)h2);
            sy += w * w;
        }

        __syncthreads();   // previous iteration's fragment reads complete
        *(f16x8*)&aH[srow][skq] = *(f16x8*)&ha[0];
        *(f16x8*)&aL[srow][skq] = *(f16x8*)&la[0];
        *(f16x8*)&bH[srow][skq] = *(f16x8*)&hb[0];
        *(f16x8*)&bL[srow][skq] = *(f16x8*)&lb[0];

        // issue next step's global loads (overlap with MFMA below)
        if (kk + 32 < Kchunk) {
            VA[0] = *(const float4*)(xp + kk + 32);
            VA[1] = *(const float4*)(xp + kk + 36);
            VB[0] = *(const float4*)(yp + kk + 32);
            VB[1] = *(const float4*)(yp + kk + 36);
        }
        __syncthreads();   // LDS tiles ready

        // fragment loads: lane l -> row (l&15), k-offset (l>>4)*8
        int fr = lane & 15, fk = (lane >> 4) * 8;
        f16x8 fAH[2], fAL[2], fBH[4], fBL[4];
#pragma unroll
        for (int mf = 0; mf < 2; ++mf) {
            fAH[mf] = *(const f16x8*)&aH[wm * 32 + mf * 16 + fr][fk];
            fAL[mf] = *(const f16x8*)&aL[wm * 32 + mf * 16 + fr][fk];
        }
#pragma unroll
        for (int nf = 0; nf < 4; ++nf) {
            fBH[nf] = *(const f16x8*)&bH[wn * 64 + nf * 16 + fr][fk];
            fBL[nf] = *(const f16x8*)&bL[wn * 64 + nf * 16 + fr][fk];
        }
#pragma unroll
        for (int mf = 0; mf < 2; ++mf)
#pragma unroll
            for (int nf = 0; nf < 4; ++nf) {
                acc[mf][nf] = __builtin_amdgcn_mfma_f32_16x16x32_f16(fAH[mf], fBH[nf], acc[mf][nf], 0, 0, 0);
                acc[mf][nf] = __builtin_amdgcn_mfma_f32_16x16x32_f16(fAH[mf], fBL[nf], acc[mf][nf], 0, 0, 0);
                acc[mf][nf] = __builtin_amdgcn_mfma_f32_16x16x32_f16(fAL[mf], fBH[nf], acc[mf][nf], 0, 0, 0);
            }
    }

    // write G partial; C-layout: col = lane&15, row = (lane>>4)*4 + reg
    size_t gb = ((size_t)(ks * B_ + b) * C_ + it * 128) * C_ + jt * 128;
#pragma unroll
    for (int mf = 0; mf < 2; ++mf)
#pragma unroll
        for (int nf = 0; nf < 4; ++nf) {
            int rr = wm * 32 + mf * 16 + (lane >> 4) * 4;
            int cc = wn * 64 + nf * 16 + (lane & 15);
#pragma unroll
            for (int r = 0; r < 4; ++r)
                Gp[gb + (size_t)(rr + r) * C_ + cc] = acc[mf][nf][r];
        }

    // norm partials: reduce the 4 lanes (t&3) that staged one row
    sx += __shfl_xor(sx, 1);
    sx += __shfl_xor(sx, 2);
    sy += __shfl_xor(sy, 1);
    sy += __shfl_xor(sy, 2);
    if (!(t & 3)) {
        if (jt == 0) x2p[(ks * B_ + b) * C_ + it * 128 + srow] = sx;
        if (it == 0) y2p[(ks * B_ + b) * C_ + jt * 128 + srow] = sy;
    }
}

// ---------------- kernel 2: reduce split-K, d2 = x2+y2-2G, argmin over j (tie -> smaller j) ----------------
__global__ __launch_bounds__(256) void argmin_kernel(const float* __restrict__ Gp,
                                                     const float* __restrict__ x2p,
                                                     const float* __restrict__ y2p,
                                                     float* __restrict__ minval,
                                                     int* __restrict__ minidx,
                                                     int KS) {
    int bi = blockIdx.x;           // b*C + i
    int b = bi >> 8;
    int i = bi & 255;
    int j = threadIdx.x;           // 0..255 == C

    float g = 0.f, sx = 0.f, sy = 0.f;
    for (int ks = 0; ks < KS; ++ks) {
        g  += Gp[((size_t)(ks * B_ + b) * C_ + i) * C_ + j];
        sx += x2p[(ks * B_ + b) * C_ + i];
        sy += y2p[(ks * B_ + b) * C_ + j];
    }

    float v = sx + sy - 2.f * g;
    int idx = j;
#pragma unroll
    for (int off = 32; off > 0; off >>= 1) {
        float v2 = __shfl_down(v, off);
        int i2 = __shfl_down(idx, off);
        if (v2 < v || (v2 == v && i2 < idx)) { v = v2; idx = i2; }
    }
    __shared__ float wv[4];
    __shared__ int wi[4];
    int lane = threadIdx.x & 63, wid = threadIdx.x >> 6;
    if (lane == 0) { wv[wid] = v; wi[wid] = idx; }
    __syncthreads();
    if (threadIdx.x == 0) {
        for (int w = 1; w < 4; ++w)
            if (wv[w] < v || (wv[w] == v && wi[w] < idx)) { v = wv[w]; idx = wi[w]; }
        minval[bi] = v;
        minidx[bi] = idx;
    }
}

// ---------------- kernel 3: per-batch stable top-128 selection + compaction ----------------
__global__ __launch_bounds__(256) void select_kernel(const float* __restrict__ minval,
                                                     const int* __restrict__ minidx,
                                                     int* __restrict__ nn) {
    int b = blockIdx.x;
    int i = threadIdx.x;           // channel
    __shared__ float vals[C_];
    __shared__ int wcnt[4];

    float v = minval[b * C_ + i];
    vals[i] = v;
    __syncthreads();

    int rank = 0;
    for (int tt = 0; tt < C_; ++tt) {
        float u = vals[tt];
        rank += (u < v) || (u == v && tt < i);
    }
    bool flag = rank < NM_;

    unsigned long long m = __ballot(flag);
    int lane = i & 63, wid = i >> 6;
    if (lane == 0) wcnt[wid] = (int)__popcll(m);
    __syncthreads();
    int off = 0;
    for (int w = 0; w < wid; ++w) off += wcnt[w];
    int pos = off + (int)__popcll(m & ((1ULL << lane) - 1ULL));
    if (flag) nn[b * NM_ + pos] = minidx[b * C_ + i];
}

// ---------------- kernel 4: gather selected Ym rows ----------------
__global__ __launch_bounds__(256) void gather_kernel(const float* __restrict__ Y,
                                                     const int* __restrict__ nn,
                                                     float* __restrict__ out) {
    int blk = blockIdx.x;
    int b = blk >> 7;
    int m = blk & 127;
    int src = nn[b * NM_ + m];
    const float4* s = (const float4*)(Y + ((size_t)b * C_ + src) * N_);
    float4* d = (float4*)(out + ((size_t)b * NM_ + m) * N_);
    for (int tt = threadIdx.x; tt < N_ / 4; tt += 256) d[tt] = s[tt];
}

extern "C" void kernel_launch(void* const* d_in, const int* in_sizes, int n_in,
                              void* d_out, int out_size, void* d_ws, size_t ws_size,
                              hipStream_t stream) {
    const float* X = (const float*)d_in[0];
    const float* Y = (const float*)d_in[1];
    float* out = (float*)d_out;

    // choose split-K factor by available workspace (exact need per KS)
    size_t favail = ws_size / 4;
    int KS = 1;
    while (KS < 16) {
        int KS2 = KS * 2;
        size_t need = (size_t)KS2 * B_ * C_ * C_          // Gp
                    + (size_t)KS2 * 2 * B_ * C_           // x2p, y2p
                    + 2 * B_ * C_ + B_ * NM_;             // minval/minidx/nn
        if (need > favail) break;
        KS = KS2;
    }
    int Kchunk = N_ / KS;

    float* minval = (float*)d_ws;
    int* minidx = (int*)(minval + B_ * C_);
    int* nn = minidx + B_ * C_;
    float* x2p = (float*)(nn + B_ * NM_);
    float* y2p = x2p + (size_t)KS * B_ * C_;
    float* Gp = y2p + (size_t)KS * B_ * C_;

    hipLaunchKernelGGL(gemm_f16_kernel, dim3(KS * 32), dim3(512), 0, stream, X, Y, Gp, x2p, y2p, Kchunk);
    hipLaunchKernelGGL(argmin_kernel, dim3(B_ * C_), dim3(256), 0, stream, Gp, x2p, y2p, minval, minidx, KS);
    hipLaunchKernelGGL(select_kernel, dim3(B_), dim3(256), 0, stream, minval, minidx, nn);
    hipLaunchKernelGGL(gather_kernel, dim3(B_ * NM_), dim3(256), 0, stream, Y, nn, out);
}

// Round 4
// 132.385 us; speedup vs baseline: 1.0190x; 1.0190x over previous
//
#include <hip/hip_runtime.h>

#define B_  8
#define C_  256
#define N_  16384
#define NM_ 128
#define LDK 40   // padded row stride (halves)

typedef _Float16 f16x8 __attribute__((ext_vector_type(8)));
typedef float    f32x4 __attribute__((ext_vector_type(4)));

// ---------------- kernel 1: split-K fp16x2 MFMA GEMM + fused norm partials ----------------
// 512 threads (8 waves), 128x128 tile, KB=32, double-buffered LDS, ONE barrier per K-step.
__global__ __launch_bounds__(512, 4) void gemm_f16_kernel(const float* __restrict__ X,
                                                          const float* __restrict__ Y,
                                                          float* __restrict__ Gp,
                                                          float* __restrict__ x2p,
                                                          float* __restrict__ y2p,
                                                          int Kchunk) {
    __shared__ _Float16 aH[2][128][LDK];
    __shared__ _Float16 aL[2][128][LDK];
    __shared__ _Float16 bH[2][128][LDK];
    __shared__ _Float16 bL[2][128][LDK];

    int lin = blockIdx.x;
    int jt = lin & 1, it = (lin >> 1) & 1, b = (lin >> 2) & 7, ks = lin >> 5;
    int k0 = ks * Kchunk;

    int t = threadIdx.x;
    int lane = t & 63;
    int wid = t >> 6;                 // 8 waves
    int wm = wid >> 1, wn = wid & 1;  // 4x2 wave grid; wave tile 32 rows x 64 cols

    int srow = t >> 2;                // staging row 0..127
    int skq = (t & 3) * 8;            // staging k sub-chunk: 0,8,16,24

    const float* xp = X + ((size_t)(b * C_) + it * 128 + srow) * N_ + k0 + skq;
    const float* yp = Y + ((size_t)(b * C_) + jt * 128 + srow) * N_ + k0 + skq;

    f32x4 acc[2][4] = {};
    float sx = 0.f, sy = 0.f;
    float4 VA[2], VB[2];

    auto prefetch = [&](int koff) {
        VA[0] = *(const float4*)(xp + koff);
        VA[1] = *(const float4*)(xp + koff + 4);
        VB[0] = *(const float4*)(yp + koff);
        VB[1] = *(const float4*)(yp + koff + 4);
    };

    auto stage_chunk = [&](int bi) {
        _Float16 ha[8], la[8], hb[8], lb[8];
        const float* fa = (const float*)VA;
        const float* fb = (const float*)VB;
#pragma unroll
        for (int e = 0; e < 8; ++e) {
            float v = fa[e];
            _Float16 h = (_Float16)v;
            ha[e] = h; la[e] = (_Float16)(v - (float)h);
            sx += v * v;
            float w = fb[e];
            _Float16 h2 = (_Float16)w;
            hb[e] = h2; lb[e] = (_Float16)(w - (float)h2);
            sy += w * w;
        }
        *(f16x8*)&aH[bi][srow][skq] = *(f16x8*)&ha[0];
        *(f16x8*)&aL[bi][srow][skq] = *(f16x8*)&la[0];
        *(f16x8*)&bH[bi][srow][skq] = *(f16x8*)&hb[0];
        *(f16x8*)&bL[bi][srow][skq] = *(f16x8*)&lb[0];
    };

    // prologue: stage chunk 0 into buf0, prefetch chunk 1
    prefetch(0);
    stage_chunk(0);
    if (Kchunk > 32) prefetch(32);

    int fr = lane & 15, fk = (lane >> 4) * 8;
    int cur = 0;

    for (int kk = 0; kk < Kchunk; kk += 32) {
        __syncthreads();   // buf[cur] writes visible; buf[cur^1] reads (prev iter) complete

        // read all fragments of this chunk first (MFMA deps resolved ASAP)
        f16x8 fAH[2], fAL[2], fBH[4], fBL[4];
#pragma unroll
        for (int mf = 0; mf < 2; ++mf) {
            fAH[mf] = *(const f16x8*)&aH[cur][wm * 32 + mf * 16 + fr][fk];
            fAL[mf] = *(const f16x8*)&aL[cur][wm * 32 + mf * 16 + fr][fk];
        }
#pragma unroll
        for (int nf = 0; nf < 4; ++nf) {
            fBH[nf] = *(const f16x8*)&bH[cur][wn * 64 + nf * 16 + fr][fk];
            fBL[nf] = *(const f16x8*)&bL[cur][wn * 64 + nf * 16 + fr][fk];
        }

        // stage chunk kk+32 into the other buffer (consumes VA/VB)
        if (kk + 32 < Kchunk) stage_chunk(cur ^ 1);
        // issue global loads for chunk kk+64 (in flight across MFMA + next barrier)
        if (kk + 64 < Kchunk) prefetch(kk + 64);

#pragma unroll
        for (int mf = 0; mf < 2; ++mf)
#pragma unroll
            for (int nf = 0; nf < 4; ++nf) {
                acc[mf][nf] = __builtin_amdgcn_mfma_f32_16x16x32_f16(fAH[mf], fBH[nf], acc[mf][nf], 0, 0, 0);
                acc[mf][nf] = __builtin_amdgcn_mfma_f32_16x16x32_f16(fAH[mf], fBL[nf], acc[mf][nf], 0, 0, 0);
                acc[mf][nf] = __builtin_amdgcn_mfma_f32_16x16x32_f16(fAL[mf], fBH[nf], acc[mf][nf], 0, 0, 0);
            }
        cur ^= 1;
    }

    // write G partial; C-layout: col = lane&15, row = (lane>>4)*4 + reg
    size_t gb = ((size_t)(ks * B_ + b) * C_ + it * 128) * C_ + jt * 128;
#pragma unroll
    for (int mf = 0; mf < 2; ++mf)
#pragma unroll
        for (int nf = 0; nf < 4; ++nf) {
            int rr = wm * 32 + mf * 16 + (lane >> 4) * 4;
            int cc = wn * 64 + nf * 16 + (lane & 15);
#pragma unroll
            for (int r = 0; r < 4; ++r)
                Gp[gb + (size_t)(rr + r) * C_ + cc] = acc[mf][nf][r];
        }

    // norm partials: reduce the 4 lanes (t&3) that staged one row
    sx += __shfl_xor(sx, 1);
    sx += __shfl_xor(sx, 2);
    sy += __shfl_xor(sy, 1);
    sy += __shfl_xor(sy, 2);
    if (!(t & 3)) {
        if (jt == 0) x2p[(ks * B_ + b) * C_ + it * 128 + srow] = sx;
        if (it == 0) y2p[(ks * B_ + b) * C_ + jt * 128 + srow] = sy;
    }
}

// ---------------- kernel 2: reduce split-K, d2 = x2+y2-2G, argmin over j (tie -> smaller j) ----------------
__global__ __launch_bounds__(256) void argmin_kernel(const float* __restrict__ Gp,
                                                     const float* __restrict__ x2p,
                                                     const float* __restrict__ y2p,
                                                     float* __restrict__ minval,
                                                     int* __restrict__ minidx,
                                                     int KS) {
    int bi = blockIdx.x;           // b*C + i
    int b = bi >> 8;
    int i = bi & 255;
    int j = threadIdx.x;           // 0..255 == C

    float g = 0.f, sx = 0.f, sy = 0.f;
    for (int ks = 0; ks < KS; ++ks) {
        g  += Gp[((size_t)(ks * B_ + b) * C_ + i) * C_ + j];
        sx += x2p[(ks * B_ + b) * C_ + i];
        sy += y2p[(ks * B_ + b) * C_ + j];
    }

    float v = sx + sy - 2.f * g;
    int idx = j;
#pragma unroll
    for (int off = 32; off > 0; off >>= 1) {
        float v2 = __shfl_down(v, off);
        int i2 = __shfl_down(idx, off);
        if (v2 < v || (v2 == v && i2 < idx)) { v = v2; idx = i2; }
    }
    __shared__ float wv[4];
    __shared__ int wi[4];
    int lane = threadIdx.x & 63, wid = threadIdx.x >> 6;
    if (lane == 0) { wv[wid] = v; wi[wid] = idx; }
    __syncthreads();
    if (threadIdx.x == 0) {
        for (int w = 1; w < 4; ++w)
            if (wv[w] < v || (wv[w] == v && wi[w] < idx)) { v = wv[w]; idx = wi[w]; }
        minval[bi] = v;
        minidx[bi] = idx;
    }
}

// ---------------- kernel 3: per-batch stable top-128 selection + compaction ----------------
__global__ __launch_bounds__(256) void select_kernel(const float* __restrict__ minval,
                                                     const int* __restrict__ minidx,
                                                     int* __restrict__ nn) {
    int b = blockIdx.x;
    int i = threadIdx.x;           // channel
    __shared__ float vals[C_];
    __shared__ int wcnt[4];

    float v = minval[b * C_ + i];
    vals[i] = v;
    __syncthreads();

    int rank = 0;
    for (int tt = 0; tt < C_; ++tt) {
        float u = vals[tt];
        rank += (u < v) || (u == v && tt < i);
    }
    bool flag = rank < NM_;

    unsigned long long m = __ballot(flag);
    int lane = i & 63, wid = i >> 6;
    if (lane == 0) wcnt[wid] = (int)__popcll(m);
    __syncthreads();
    int off = 0;
    for (int w = 0; w < wid; ++w) off += wcnt[w];
    int pos = off + (int)__popcll(m & ((1ULL << lane) - 1ULL));
    if (flag) nn[b * NM_ + pos] = minidx[b * C_ + i];
}

// ---------------- kernel 4: gather selected Ym rows ----------------
__global__ __launch_bounds__(256) void gather_kernel(const float* __restrict__ Y,
                                                     const int* __restrict__ nn,
                                                     float* __restrict__ out) {
    int blk = blockIdx.x;
    int b = blk >> 7;
    int m = blk & 127;
    int src = nn[b * NM_ + m];
    const float4* s = (const float4*)(Y + ((size_t)b * C_ + src) * N_);
    float4* d = (float4*)(out + ((size_t)b * NM_ + m) * N_);
    for (int tt = threadIdx.x; tt < N_ / 4; tt += 256) d[tt] = s[tt];
}

extern "C" void kernel_launch(void* const* d_in, const int* in_sizes, int n_in,
                              void* d_out, int out_size, void* d_ws, size_t ws_size,
                              hipStream_t stream) {
    const float* X = (const float*)d_in[0];
    const float* Y = (const float*)d_in[1];
    float* out = (float*)d_out;

    // choose split-K factor by available workspace (exact need per KS)
    size_t favail = ws_size / 4;
    int KS = 1;
    while (KS < 16) {
        int KS2 = KS * 2;
        size_t need = (size_t)KS2 * B_ * C_ * C_          // Gp
                    + (size_t)KS2 * 2 * B_ * C_           // x2p, y2p
                    + 2 * B_ * C_ + B_ * NM_;             // minval/minidx/nn
        if (need > favail) break;
        KS = KS2;
    }
    int Kchunk = N_ / KS;

    float* minval = (float*)d_ws;
    int* minidx = (int*)(minval + B_ * C_);
    int* nn = minidx + B_ * C_;
    float* x2p = (float*)(nn + B_ * NM_);
    float* y2p = x2p + (size_t)KS * B_ * C_;
    float* Gp = y2p + (size_t)KS * B_ * C_;

    hipLaunchKernelGGL(gemm_f16_kernel, dim3(KS * 32), dim3(512), 0, stream, X, Y, Gp, x2p, y2p, Kchunk);
    hipLaunchKernelGGL(argmin_kernel, dim3(B_ * C_), dim3(256), 0, stream, Gp, x2p, y2p, minval, minidx, KS);
    hipLaunchKernelGGL(select_kernel, dim3(B_), dim3(256), 0, stream, minval, minidx, nn);
    hipLaunchKernelGGL(gather_kernel, dim3(B_ * NM_), dim3(256), 0, stream, Y, nn, out);
}

// Round 5
// 127.715 us; speedup vs baseline: 1.0563x; 1.0366x over previous
//
#include <hip/hip_runtime.h>

#define B_  8
#define C_  256
#define N_  16384
#define NM_ 128
#define LDK 40   // padded row stride (halves)

typedef _Float16 f16x8 __attribute__((ext_vector_type(8)));
typedef float    f32x4 __attribute__((ext_vector_type(4)));

// ---------------- kernel 1: split-K fp16x2 MFMA GEMM + fused norm partials ----------------
// 512 threads (8 waves), 128x128 tile, KB=32, double-buffered LDS, ONE barrier per K-step.
// amdgpu_waves_per_eu(4,4): pin allocator to 4 waves/EU (<=128 VGPR) so the 90-reg live set
// fits without spills (r2-r4 all allocated 60-64 VGPR and were spill/serialization-bound).
__global__ __launch_bounds__(512)
__attribute__((amdgpu_waves_per_eu(4, 4)))
void gemm_f16_kernel(const float* __restrict__ X,
                     const float* __restrict__ Y,
                     float* __restrict__ Gp,
                     float* __restrict__ x2p,
                     float* __restrict__ y2p,
                     int Kchunk) {
    __shared__ _Float16 aH[2][128][LDK];
    __shared__ _Float16 aL[2][128][LDK];
    __shared__ _Float16 bH[2][128][LDK];
    __shared__ _Float16 bL[2][128][LDK];

    int lin = blockIdx.x;
    int jt = lin & 1, it = (lin >> 1) & 1, b = (lin >> 2) & 7, ks = lin >> 5;
    int k0 = ks * Kchunk;

    int t = threadIdx.x;
    int lane = t & 63;
    int wid = t >> 6;                 // 8 waves
    int wm = wid >> 1, wn = wid & 1;  // 4x2 wave grid; wave tile 32 rows x 64 cols

    int srow = t >> 2;                // staging row 0..127
    int skq = (t & 3) * 8;            // staging k sub-chunk: 0,8,16,24

    const float* xp = X + ((size_t)(b * C_) + it * 128 + srow) * N_ + k0 + skq;
    const float* yp = Y + ((size_t)(b * C_) + jt * 128 + srow) * N_ + k0 + skq;

    f32x4 acc[2][4] = {};
    float sx = 0.f, sy = 0.f;
    float4 VA[2], VB[2];

    auto prefetch = [&](int koff) {
        VA[0] = *(const float4*)(xp + koff);
        VA[1] = *(const float4*)(xp + koff + 4);
        VB[0] = *(const float4*)(yp + koff);
        VB[1] = *(const float4*)(yp + koff + 4);
    };

    auto stage_chunk = [&](int bi) {
        _Float16 ha[8], la[8], hb[8], lb[8];
        const float* fa = (const float*)VA;
        const float* fb = (const float*)VB;
#pragma unroll
        for (int e = 0; e < 8; ++e) {
            float v = fa[e];
            _Float16 h = (_Float16)v;
            ha[e] = h; la[e] = (_Float16)(v - (float)h);
            sx += v * v;
            float w = fb[e];
            _Float16 h2 = (_Float16)w;
            hb[e] = h2; lb[e] = (_Float16)(w - (float)h2);
            sy += w * w;
        }
        *(f16x8*)&aH[bi][srow][skq] = *(f16x8*)&ha[0];
        *(f16x8*)&aL[bi][srow][skq] = *(f16x8*)&la[0];
        *(f16x8*)&bH[bi][srow][skq] = *(f16x8*)&hb[0];
        *(f16x8*)&bL[bi][srow][skq] = *(f16x8*)&lb[0];
    };

    // prologue: stage chunk 0 into buf0, prefetch chunk 1
    prefetch(0);
    stage_chunk(0);
    if (Kchunk > 32) prefetch(32);

    int fr = lane & 15, fk = (lane >> 4) * 8;
    int cur = 0;

    for (int kk = 0; kk < Kchunk; kk += 32) {
        __syncthreads();   // buf[cur] writes visible; buf[cur^1] reads (prev iter) complete

        // persistent A fragments for this step (4 frags = 16 VGPR)
        f16x8 fAH0 = *(const f16x8*)&aH[cur][wm * 32 +  0 + fr][fk];
        f16x8 fAH1 = *(const f16x8*)&aH[cur][wm * 32 + 16 + fr][fk];
        f16x8 fAL0 = *(const f16x8*)&aL[cur][wm * 32 +  0 + fr][fk];
        f16x8 fAL1 = *(const f16x8*)&aL[cur][wm * 32 + 16 + fr][fk];

        // stage chunk kk+32 into the other buffer (consumes VA/VB)
        if (kk + 32 < Kchunk) stage_chunk(cur ^ 1);
        // issue global loads for chunk kk+64 (in flight across MFMA + next barrier)
        if (kk + 64 < Kchunk) prefetch(kk + 64);

        // B fragments loaded per-nf: only 2 live at a time (8 VGPR)
#pragma unroll
        for (int nf = 0; nf < 4; ++nf) {
            f16x8 fBH = *(const f16x8*)&bH[cur][wn * 64 + nf * 16 + fr][fk];
            f16x8 fBL = *(const f16x8*)&bL[cur][wn * 64 + nf * 16 + fr][fk];
            acc[0][nf] = __builtin_amdgcn_mfma_f32_16x16x32_f16(fAH0, fBH, acc[0][nf], 0, 0, 0);
            acc[1][nf] = __builtin_amdgcn_mfma_f32_16x16x32_f16(fAH1, fBH, acc[1][nf], 0, 0, 0);
            acc[0][nf] = __builtin_amdgcn_mfma_f32_16x16x32_f16(fAH0, fBL, acc[0][nf], 0, 0, 0);
            acc[1][nf] = __builtin_amdgcn_mfma_f32_16x16x32_f16(fAH1, fBL, acc[1][nf], 0, 0, 0);
            acc[0][nf] = __builtin_amdgcn_mfma_f32_16x16x32_f16(fAL0, fBH, acc[0][nf], 0, 0, 0);
            acc[1][nf] = __builtin_amdgcn_mfma_f32_16x16x32_f16(fAL1, fBH, acc[1][nf], 0, 0, 0);
        }
        cur ^= 1;
    }

    // write G partial; C-layout: col = lane&15, row = (lane>>4)*4 + reg
    size_t gb = ((size_t)(ks * B_ + b) * C_ + it * 128) * C_ + jt * 128;
#pragma unroll
    for (int mf = 0; mf < 2; ++mf)
#pragma unroll
        for (int nf = 0; nf < 4; ++nf) {
            int rr = wm * 32 + mf * 16 + (lane >> 4) * 4;
            int cc = wn * 64 + nf * 16 + (lane & 15);
#pragma unroll
            for (int r = 0; r < 4; ++r)
                Gp[gb + (size_t)(rr + r) * C_ + cc] = acc[mf][nf][r];
        }

    // norm partials: reduce the 4 lanes (t&3) that staged one row
    sx += __shfl_xor(sx, 1);
    sx += __shfl_xor(sx, 2);
    sy += __shfl_xor(sy, 1);
    sy += __shfl_xor(sy, 2);
    if (!(t & 3)) {
        if (jt == 0) x2p[(ks * B_ + b) * C_ + it * 128 + srow] = sx;
        if (it == 0) y2p[(ks * B_ + b) * C_ + jt * 128 + srow] = sy;
    }
}

// ---------------- kernel 2: reduce split-K, d2 = x2+y2-2G, argmin over j (tie -> smaller j) ----------------
__global__ __launch_bounds__(256) void argmin_kernel(const float* __restrict__ Gp,
                                                     const float* __restrict__ x2p,
                                                     const float* __restrict__ y2p,
                                                     float* __restrict__ minval,
                                                     int* __restrict__ minidx,
                                                     int KS) {
    int bi = blockIdx.x;           // b*C + i
    int b = bi >> 8;
    int i = bi & 255;
    int j = threadIdx.x;           // 0..255 == C

    float g = 0.f, sx = 0.f, sy = 0.f;
    for (int ks = 0; ks < KS; ++ks) {
        g  += Gp[((size_t)(ks * B_ + b) * C_ + i) * C_ + j];
        sx += x2p[(ks * B_ + b) * C_ + i];
        sy += y2p[(ks * B_ + b) * C_ + j];
    }

    float v = sx + sy - 2.f * g;
    int idx = j;
#pragma unroll
    for (int off = 32; off > 0; off >>= 1) {
        float v2 = __shfl_down(v, off);
        int i2 = __shfl_down(idx, off);
        if (v2 < v || (v2 == v && i2 < idx)) { v = v2; idx = i2; }
    }
    __shared__ float wv[4];
    __shared__ int wi[4];
    int lane = threadIdx.x & 63, wid = threadIdx.x >> 6;
    if (lane == 0) { wv[wid] = v; wi[wid] = idx; }
    __syncthreads();
    if (threadIdx.x == 0) {
        for (int w = 1; w < 4; ++w)
            if (wv[w] < v || (wv[w] == v && wi[w] < idx)) { v = wv[w]; idx = wi[w]; }
        minval[bi] = v;
        minidx[bi] = idx;
    }
}

// ---------------- kernel 3: per-batch stable top-128 selection + compaction ----------------
__global__ __launch_bounds__(256) void select_kernel(const float* __restrict__ minval,
                                                     const int* __restrict__ minidx,
                                                     int* __restrict__ nn) {
    int b = blockIdx.x;
    int i = threadIdx.x;           // channel
    __shared__ float vals[C_];
    __shared__ int wcnt[4];

    float v = minval[b * C_ + i];
    vals[i] = v;
    __syncthreads();

    int rank = 0;
    for (int tt = 0; tt < C_; ++tt) {
        float u = vals[tt];
        rank += (u < v) || (u == v && tt < i);
    }
    bool flag = rank < NM_;

    unsigned long long m = __ballot(flag);
    int lane = i & 63, wid = i >> 6;
    if (lane == 0) wcnt[wid] = (int)__popcll(m);
    __syncthreads();
    int off = 0;
    for (int w = 0; w < wid; ++w) off += wcnt[w];
    int pos = off + (int)__popcll(m & ((1ULL << lane) - 1ULL));
    if (flag) nn[b * NM_ + pos] = minidx[b * C_ + i];
}

// ---------------- kernel 4: gather selected Ym rows ----------------
__global__ __launch_bounds__(256) void gather_kernel(const float* __restrict__ Y,
                                                     const int* __restrict__ nn,
                                                     float* __restrict__ out) {
    int blk = blockIdx.x;
    int b = blk >> 7;
    int m = blk & 127;
    int src = nn[b * NM_ + m];
    const float4* s = (const float4*)(Y + ((size_t)b * C_ + src) * N_);
    float4* d = (float4*)(out + ((size_t)b * NM_ + m) * N_);
    for (int tt = threadIdx.x; tt < N_ / 4; tt += 256) d[tt] = s[tt];
}

extern "C" void kernel_launch(void* const* d_in, const int* in_sizes, int n_in,
                              void* d_out, int out_size, void* d_ws, size_t ws_size,
                              hipStream_t stream) {
    const float* X = (const float*)d_in[0];
    const float* Y = (const float*)d_in[1];
    float* out = (float*)d_out;

    // choose split-K factor by available workspace (exact need per KS)
    size_t favail = ws_size / 4;
    int KS = 1;
    while (KS < 16) {
        int KS2 = KS * 2;
        size_t need = (size_t)KS2 * B_ * C_ * C_          // Gp
                    + (size_t)KS2 * 2 * B_ * C_           // x2p, y2p
                    + 2 * B_ * C_ + B_ * NM_;             // minval/minidx/nn
        if (need > favail) break;
        KS = KS2;
    }
    int Kchunk = N_ / KS;

    float* minval = (float*)d_ws;
    int* minidx = (int*)(minval + B_ * C_);
    int* nn = minidx + B_ * C_;
    float* x2p = (float*)(nn + B_ * NM_);
    float* y2p = x2p + (size_t)KS * B_ * C_;
    float* Gp = y2p + (size_t)KS * B_ * C_;

    hipLaunchKernelGGL(gemm_f16_kernel, dim3(KS * 32), dim3(512), 0, stream, X, Y, Gp, x2p, y2p, Kchunk);
    hipLaunchKernelGGL(argmin_kernel, dim3(B_ * C_), dim3(256), 0, stream, Gp, x2p, y2p, minval, minidx, KS);
    hipLaunchKernelGGL(select_kernel, dim3(B_), dim3(256), 0, stream, minval, minidx, nn);
    hipLaunchKernelGGL(gather_kernel, dim3(B_ * NM_), dim3(256), 0, stream, Y, nn, out);
}